// Round 15
// baseline (211.554 us; speedup 1.0000x reference)
//
#include <hip/hip_runtime.h>
#include <hip/hip_bf16.h>

#define T_TOK 2048
#define H_DIM 1024
#define E_N   8
#define I_DIM 2048
#define GW    4096        // gbuf row width (gate|up concat)

#define NT_MAX 24         // sum ceil(cnt_e/256) <= 4096/256 + 8 = 24
#define SLOTS  6144       // 24 tiles * 256 rows

typedef unsigned short u16;
typedef unsigned int   u32;
typedef __bf16 bf16_t;
typedef bf16_t bf16x8 __attribute__((ext_vector_type(8)));
typedef u16    u16x8  __attribute__((ext_vector_type(8)));
typedef u16    u16x4  __attribute__((ext_vector_type(4)));
typedef float  f32x16 __attribute__((ext_vector_type(16)));

#define MFMA32 __builtin_amdgcn_mfma_f32_32x32x16_bf16
#define SB()   __builtin_amdgcn_sched_barrier(0)

__device__ __forceinline__ u16 bfbits(float f) {
    bf16_t b = (bf16_t)f;
    return __builtin_bit_cast(u16, b);
}
__device__ __forceinline__ float bf2f(u16 u) {
    u32 x = ((u32)u) << 16;
    return __builtin_bit_cast(float, x);
}

__device__ __forceinline__ void gload_lds16(const void* g, void* l) {
    __builtin_amdgcn_global_load_lds(
        (const __attribute__((address_space(1))) void*)g,
        (__attribute__((address_space(3))) void*)l, 16, 0, 0);
}

// B LDS tile: col n (0..127), k-slot kb (0..7)
__device__ __forceinline__ int tile_off(int n, int kb) {
    return n * 64 + ((kb ^ ((n >> 1) & 7)) << 3);
}
// A LDS tile (linear gload_lds dest, source k-group pre-XOR'd): row (0..255), kslot
__device__ __forceinline__ int a_off(int row, int kslot) {
    return row * 64 + ((kslot ^ (row & 7)) << 3);
}

// ---------------- router: 4 tokens/block; float4 loads; lists + inverse map
__global__ __launch_bounds__(256) void router_k(
    const float* __restrict__ x, const float* __restrict__ rw,
    int* __restrict__ cnt, int* __restrict__ tok,
    int4* __restrict__ invA, float2* __restrict__ invW,
    u16* __restrict__ xbf)
{
    int wid = threadIdx.x >> 6, lane = threadIdx.x & 63;
    int t = blockIdx.x * 4 + wid;
    const float* xr = x + (size_t)t * H_DIM;
    u16* xbr = xbf + (size_t)t * H_DIM;

    float acc[E_N];
#pragma unroll
    for (int e = 0; e < E_N; e++) acc[e] = 0.f;
#pragma unroll
    for (int j = 0; j < H_DIM / 256; j++) {
        int o = lane * 4 + j * 256;
        float4 xv = *reinterpret_cast<const float4*>(xr + o);
        u16x4 p;
        p[0] = bfbits(xv.x); p[1] = bfbits(xv.y); p[2] = bfbits(xv.z); p[3] = bfbits(xv.w);
        *reinterpret_cast<u16x4*>(xbr + o) = p;
#pragma unroll
        for (int e = 0; e < E_N; e++) {
            float4 wv = *reinterpret_cast<const float4*>(rw + e * H_DIM + o);
            acc[e] += xv.x * wv.x + xv.y * wv.y + xv.z * wv.z + xv.w * wv.w;
        }
    }
#pragma unroll
    for (int e = 0; e < E_N; e++) {
        float v = acc[e];
        for (int off = 32; off; off >>= 1) v += __shfl_xor(v, off);
        acc[e] = v;
    }
    if (lane == 0) {
        int i0 = 0; float m0 = acc[0];
#pragma unroll
        for (int e = 1; e < E_N; e++) if (acc[e] > m0) { m0 = acc[e]; i0 = e; }
        int i1 = -1; float m1 = -INFINITY;
#pragma unroll
        for (int e = 0; e < E_N; e++) if (e != i0 && acc[e] > m1) { m1 = acc[e]; i1 = e; }
        float w0 = 1.f / (1.f + expf(m1 - m0));
        float w1 = 1.f - w0;
        int p0 = atomicAdd(&cnt[i0], 1);
        tok[i0 * T_TOK + p0] = t;
        int p1 = atomicAdd(&cnt[i1], 1);
        tok[i1 * T_TOK + p1] = t;
        invA[t] = make_int4(i0, p0, i1, p1);
        invW[t] = make_float2(w0, w1);
    }
}

// ---------------- prefix + padded tile map (BM=256)
__global__ void prefix_k(const int* __restrict__ cnt, int* __restrict__ offs_pad,
                         int* __restrict__ tile_e, int* __restrict__ tile_row0,
                         int* __restrict__ ntiles)
{
    if (threadIdx.x == 0) {
        int s = 0, nt = 0;
        for (int e = 0; e < E_N; e++) {
            offs_pad[e] = s;
            int c = cnt[e];
            int t = (c + 255) >> 8;
            for (int i = 0; i < t; i++) { tile_e[nt] = e; tile_row0[nt] = i * 256; nt++; }
            s += t * 256;
        }
        offs_pad[E_N] = s;
        *ntiles = nt;
    }
}

// ---------------- combined gate|up grouped GEMM (N = 4096 concat), fused cvt.
// tile 256x128, BK=64, 8 waves (4M x 2N), wave tile 64x64, MFMA32.
// LDS: A dbuf 2x32KB + single B 16KB = 80KB -> 2 blocks/CU; 16 waves/CU.
// iter t: ASTAGE(ab^1,t+1); BLOAD(t+1); CLUSTER(ab); s_barrier;
//         BWRITE (implicit reg wait retires A too, FIFO); vmcnt0+lgkm0; s_barrier.
__global__ __launch_bounds__(512, 4) void gu_k(
    const u16* __restrict__ xbf, const float* __restrict__ wg, const float* __restrict__ wu,
    const int* __restrict__ cnt, const int* __restrict__ offs_pad,
    const int* __restrict__ tile_e, const int* __restrict__ tile_row0,
    const int* __restrict__ ntiles, const int* __restrict__ tok,
    u16* __restrict__ gbuf)
{
    int q = gridDim.x >> 3;
    int phys = blockIdx.x;
    int logical = (phys & 7) * q + (phys >> 3);
    int tb = logical % NT_MAX;
    int p  = logical / NT_MAX;             // 0..31 over GW=4096
    if (tb >= *ntiles) return;
    int e = tile_e[tb], row0 = tile_row0[tb];
    int cntE = cnt[e];
    int slot0 = offs_pad[e] + row0;
    int n0 = p * 128;
    int mat  = n0 >> 11;                   // 0: gate, 1: up
    int coln = n0 & 2047;

    __shared__ u16 AS[2][16384], BS[8192]; // 80 KB

    int tid = threadIdx.x;
    int lane = tid & 63, wid = tid >> 6;   // 8 waves
    int wm = wid >> 1, wn = wid & 1;       // 4M x 2N
    int l31 = lane & 31, lh = lane >> 5;

    // A staging: 32 gloads/tile, 4 per wave; wave wid covers rows wid*32..wid*32+31
    const u16* asrc[4];
#pragma unroll
    for (int i = 0; i < 4; i++) {
        int row = wid * 32 + i * 8 + (lane >> 3);
        int rc = (row0 + row < cntE) ? (row0 + row) : (cntE - 1);
        asrc[i] = xbf + (size_t)tok[e * T_TOK + rc] * H_DIM
                  + (((lane & 7) ^ ((lane >> 3) & 7)) << 3);
    }
    int s0 = wid * 2048;                   // u16 offset of wave's 32 rows

    // B staging: thread owns column bn, k-quarter kq (16 k's)
    int bn = tid & 127;
    int kq = tid >> 7;                     // 0..3
    const float* wsrc = (mat ? wu : wg) + (size_t)e * H_DIM * I_DIM + coln + bn;

    float v[16];

#define BLOAD(t) { \
    _Pragma("unroll") \
    for (int j = 0; j < 16; j++) \
        v[j] = wsrc[(size_t)((t) * 64 + kq * 16 + j) * I_DIM]; }

#define BWRITE() { \
    _Pragma("unroll") \
    for (int jb = 0; jb < 2; jb++) { \
        u16x8 pk; \
        _Pragma("unroll") \
        for (int jj = 0; jj < 8; jj++) pk[jj] = bfbits(v[jb * 8 + jj]); \
        *reinterpret_cast<u16x8*>(&BS[tile_off(bn, kq * 2 + jb)]) = pk; } }

#define ASTAGE(nbuf, t) { \
    _Pragma("unroll") \
    for (int i = 0; i < 4; i++) \
        gload_lds16(asrc[i] + (size_t)(t) * 64, &AS[nbuf][s0 + i * 512]); }

    f32x16 acc[2][2];
#pragma unroll
    for (int a = 0; a < 2; a++)
#pragma unroll
        for (int b = 0; b < 2; b++) acc[a][b] = (f32x16)0.f;

#define CLUSTER(bufi) { \
    _Pragma("unroll") \
    for (int ks = 0; ks < 4; ks++) { \
        bf16x8 af[2], bfr[2]; \
        _Pragma("unroll") \
        for (int mf = 0; mf < 2; mf++) \
            af[mf] = *reinterpret_cast<const bf16x8*>(&AS[bufi][a_off(wm * 64 + mf * 32 + l31, ks * 2 + lh)]); \
        _Pragma("unroll") \
        for (int nf = 0; nf < 2; nf++) \
            bfr[nf] = *reinterpret_cast<const bf16x8*>(&BS[tile_off(wn * 64 + nf * 32 + l31, ks * 2 + lh)]); \
        _Pragma("unroll") \
        for (int mf = 0; mf < 2; mf++) \
            _Pragma("unroll") \
            for (int nf = 0; nf < 2; nf++) \
                acc[mf][nf] = MFMA32(af[mf], bfr[nf], acc[mf][nf], 0, 0, 0); } }

    // prologue (pinned, one full drain)
    ASTAGE(0, 0);
    SB();
    BLOAD(0);
    SB();
    BWRITE();
    SB();
    asm volatile("s_waitcnt vmcnt(0) lgkmcnt(0)" ::: "memory");
    __builtin_amdgcn_s_barrier();
    SB();

    for (int t = 0; t < 16; t++) {
        int ab = t & 1;
        bool more = (t + 1) < 16;
        if (more) {
            ASTAGE(ab ^ 1, t + 1);         // in flight across whole iteration
            SB();
            BLOAD(t + 1);                  // cover = CLUSTER
            SB();
        }
        CLUSTER(ab);
        SB();
        __builtin_amdgcn_s_barrier();      // BS + AS[ab] readers done
        SB();
        if (more) {
            BWRITE();                      // reg wait retires B(t+1) AND A(t+1) (FIFO)
            SB();
            asm volatile("s_waitcnt vmcnt(0) lgkmcnt(0)" ::: "memory");
            __builtin_amdgcn_s_barrier();  // BS(t+1) + AS[ab^1] visible
            SB();
        }
    }
#undef BLOAD
#undef BWRITE
#undef ASTAGE
#undef CLUSTER

    // epilogue: raw store (silu applied in-place by act_k); padded rows harmless
#pragma unroll
    for (int mf = 0; mf < 2; mf++)
#pragma unroll
        for (int nf = 0; nf < 2; nf++) {
            int col = n0 + wn * 64 + nf * 32 + l31;
#pragma unroll
            for (int r = 0; r < 16; r++) {
                int rl = wm * 64 + mf * 32 + (r & 3) + 8 * (r >> 2) + 4 * lh;
                gbuf[(size_t)(slot0 + rl) * GW + col] = bfbits(acc[mf][nf][r]);
            }
        }
}

// ---------------- act in-place: gbuf[s][0..2047] = silu(gate) * up
__global__ __launch_bounds__(256) void act_k(u16* __restrict__ gbuf)
{
    int s = blockIdx.x;
    int i = threadIdx.x * 8;
    u16x8 g8 = *reinterpret_cast<const u16x8*>(&gbuf[(size_t)s * GW + i]);
    u16x8 u8 = *reinterpret_cast<const u16x8*>(&gbuf[(size_t)s * GW + 2048 + i]);
    u16x8 o;
#pragma unroll
    for (int j = 0; j < 8; j++) {
        float g = bf2f(g8[j]);
        float u = bf2f(u8[j]);
        o[j] = bfbits(g / (1.f + expf(-g)) * u);
    }
    *reinterpret_cast<u16x8*>(&gbuf[(size_t)s * GW + i]) = o;
}

// ---------------- down grouped GEMM: dbuf[kq][slot] = act @ w_down[e], K split 4
// tile 256x128, 8 waves, same pipeline. A = gbuf gate half (row stride GW).
__global__ __launch_bounds__(512, 4) void down_k(
    const u16* __restrict__ gbuf, const float* __restrict__ wd,
    const int* __restrict__ cnt, const int* __restrict__ offs_pad,
    const int* __restrict__ tile_e, const int* __restrict__ tile_row0,
    const int* __restrict__ ntiles, const int* __restrict__ tok,
    u16* __restrict__ dbuf)
{
    int q = gridDim.x >> 3;
    int phys = blockIdx.x;
    int logical = (phys & 7) * q + (phys >> 3);
    int tb = logical % NT_MAX;
    int rest = logical / NT_MAX;           // 0..31
    int p   = rest & 7;                    // h-panel 0..7
    int kq4 = rest >> 3;                   // K quarter 0..3 (512 each)
    if (tb >= *ntiles) return;
    int e = tile_e[tb], row0 = tile_row0[tb];
    int slot0 = offs_pad[e] + row0;
    int h0 = p * 128;

    __shared__ u16 AS[2][16384], BS[8192]; // 80 KB

    int tid = threadIdx.x;
    int lane = tid & 63, wid = tid >> 6;
    int wm = wid >> 1, wn = wid & 1;
    int l31 = lane & 31, lh = lane >> 5;

    const u16* asrc[4];
#pragma unroll
    for (int i = 0; i < 4; i++) {
        int row = wid * 32 + i * 8 + (lane >> 3);
        asrc[i] = gbuf + (size_t)(slot0 + row) * GW + kq4 * 512
                  + (((lane & 7) ^ ((lane >> 3) & 7)) << 3);
    }
    int s0 = wid * 2048;

    int bn = tid & 127;
    int kq = tid >> 7;                     // 0..3, 16 k's each
    const float* dsrc = wd + ((size_t)e * I_DIM + kq4 * 512) * H_DIM + h0 + bn;

    float v[16];

#define BLOAD(t) { \
    _Pragma("unroll") \
    for (int j = 0; j < 16; j++) \
        v[j] = dsrc[(size_t)((t) * 64 + kq * 16 + j) * H_DIM]; }

#define BWRITE() { \
    _Pragma("unroll") \
    for (int jb = 0; jb < 2; jb++) { \
        u16x8 pk; \
        _Pragma("unroll") \
        for (int jj = 0; jj < 8; jj++) pk[jj] = bfbits(v[jb * 8 + jj]); \
        *reinterpret_cast<u16x8*>(&BS[tile_off(bn, kq * 2 + jb)]) = pk; } }

#define ASTAGE(nbuf, t) { \
    _Pragma("unroll") \
    for (int i = 0; i < 4; i++) \
        gload_lds16(asrc[i] + (size_t)(t) * 64, &AS[nbuf][s0 + i * 512]); }

    f32x16 acc[2][2];
#pragma unroll
    for (int a = 0; a < 2; a++)
#pragma unroll
        for (int b = 0; b < 2; b++) acc[a][b] = (f32x16)0.f;

#define CLUSTER(bufi) { \
    _Pragma("unroll") \
    for (int ks = 0; ks < 4; ks++) { \
        bf16x8 af[2], bfr[2]; \
        _Pragma("unroll") \
        for (int mf = 0; mf < 2; mf++) \
            af[mf] = *reinterpret_cast<const bf16x8*>(&AS[bufi][a_off(wm * 64 + mf * 32 + l31, ks * 2 + lh)]); \
        _Pragma("unroll") \
        for (int nf = 0; nf < 2; nf++) \
            bfr[nf] = *reinterpret_cast<const bf16x8*>(&BS[tile_off(wn * 64 + nf * 32 + l31, ks * 2 + lh)]); \
        _Pragma("unroll") \
        for (int mf = 0; mf < 2; mf++) \
            _Pragma("unroll") \
            for (int nf = 0; nf < 2; nf++) \
                acc[mf][nf] = MFMA32(af[mf], bfr[nf], acc[mf][nf], 0, 0, 0); } }

    ASTAGE(0, 0);
    SB();
    BLOAD(0);
    SB();
    BWRITE();
    SB();
    asm volatile("s_waitcnt vmcnt(0) lgkmcnt(0)" ::: "memory");
    __builtin_amdgcn_s_barrier();
    SB();

    for (int t = 0; t < 8; t++) {
        int ab = t & 1;
        bool more = (t + 1) < 8;
        if (more) {
            ASTAGE(ab ^ 1, t + 1);
            SB();
            BLOAD(t + 1);
            SB();
        }
        CLUSTER(ab);
        SB();
        __builtin_amdgcn_s_barrier();
        SB();
        if (more) {
            BWRITE();
            SB();
            asm volatile("s_waitcnt vmcnt(0) lgkmcnt(0)" ::: "memory");
            __builtin_amdgcn_s_barrier();
            SB();
        }
    }
#undef BLOAD
#undef BWRITE
#undef ASTAGE
#undef CLUSTER

#pragma unroll
    for (int mf = 0; mf < 2; mf++)
#pragma unroll
        for (int nf = 0; nf < 2; nf++) {
            int col = h0 + wn * 64 + nf * 32 + l31;
#pragma unroll
            for (int r = 0; r < 16; r++) {
                int rl = wm * 64 + mf * 32 + (r & 3) + 8 * (r >> 2) + 4 * lh;
                dbuf[(size_t)(kq4 * SLOTS + slot0 + rl) * H_DIM + col] = bfbits(acc[mf][nf][r]);
            }
        }
}

// ---------------- gather: out[t][h] = sum over 4 K-quarters, 2 experts, weighted
__global__ __launch_bounds__(256) void gather_k(
    const u16* __restrict__ dbuf, const int4* __restrict__ invA,
    const float2* __restrict__ invW, const int* __restrict__ offs_pad,
    float* __restrict__ out)
{
    int t = blockIdx.x;
    int h = threadIdx.x * 4;
    int4 ia = invA[t];
    float2 w = invW[t];
    int s0 = offs_pad[ia.x] + ia.y;
    int s1 = offs_pad[ia.z] + ia.w;

    float4 o = make_float4(0.f, 0.f, 0.f, 0.f);
    float* op = &o.x;
#pragma unroll
    for (int qk = 0; qk < 4; qk++) {
        u16x4 a = *reinterpret_cast<const u16x4*>(&dbuf[(size_t)(qk * SLOTS + s0) * H_DIM + h]);
        u16x4 b = *reinterpret_cast<const u16x4*>(&dbuf[(size_t)(qk * SLOTS + s1) * H_DIM + h]);
#pragma unroll
        for (int j = 0; j < 4; j++)
            op[j] += w.x * bf2f(a[j]) + w.y * bf2f(b[j]);
    }
    *reinterpret_cast<float4*>(&out[(size_t)t * H_DIM + h]) = o;
}

extern "C" void kernel_launch(void* const* d_in, const int* in_sizes, int n_in,
                              void* d_out, int out_size, void* d_ws, size_t ws_size,
                              hipStream_t stream)
{
    const float* x  = (const float*)d_in[0];
    const float* rw = (const float*)d_in[1];
    const float* wg = (const float*)d_in[2];
    const float* wu = (const float*)d_in[3];
    const float* wd = (const float*)d_in[4];
    float* out = (float*)d_out;

    char* ws = (char*)d_ws;
    int*    cnt       = (int*)(ws);
    int*    ntiles    = (int*)(ws + 32);
    int*    offs_pad  = (int*)(ws + 64);
    int*    tile_e    = (int*)(ws + 256);
    int*    tile_row0 = (int*)(ws + 512);
    int*    tok       = (int*)(ws + 64 * 1024);            // 64 KB
    int4*   invA      = (int4*)(ws + 160 * 1024);          // 32 KB
    float2* invW      = (float2*)(ws + 200 * 1024);        // 16 KB
    u16*    xbf       = (u16*)(ws + 256 * 1024);           // 4 MB
    u16*    gbuf      = (u16*)(ws + 5ull * 1024 * 1024);   // 6144*4096*2 = 48 MB
    u16*    dbuf      = (u16*)(ws + 53ull * 1024 * 1024);  // 4*6144*1024*2 = 48 MB

    size_t need = 102ull * 1024 * 1024;
    if (ws_size < need) return;

    hipMemsetAsync(cnt, 0, 32, stream);

    router_k<<<T_TOK / 4, 256, 0, stream>>>(x, rw, cnt, tok, invA, invW, xbf);
    prefix_k<<<1, 64, 0, stream>>>(cnt, offs_pad, tile_e, tile_row0, ntiles);
    gu_k<<<NT_MAX * (GW / 128), 512, 0, stream>>>(
        xbf, wg, wu, cnt, offs_pad, tile_e, tile_row0, ntiles, tok, gbuf);
    act_k<<<SLOTS, 256, 0, stream>>>(gbuf);
    down_k<<<NT_MAX * (H_DIM / 128) * 4, 512, 0, stream>>>(
        gbuf, wd, cnt, offs_pad, tile_e, tile_row0, ntiles, tok, dbuf);
    gather_k<<<T_TOK, 256, 0, stream>>>(dbuf, invA, invW, offs_pad, out);
}